// Round 1
// baseline (140.314 us; speedup 1.0000x reference)
//
#include <hip/hip_runtime.h>
#include <math.h>

#define NUM_TOKENS 16384
#define NUM_HEADS  32
#define HEAD_SIZE  128

// One 32-lane sub-group handles one (token, head) pair:
//   - 32 lanes x float4 = 128 floats of prefix/suffix output (coalesced 16B/lane)
//   - per-pair LSE math recomputed per lane (broadcast loads, cheap)
//   - lane 0 writes merged LSE
__global__ __launch_bounds__(256) void merge_attn_states_kernel(
    const float* __restrict__ p_out,   // [NUM_TOKENS, NUM_HEADS, HEAD_SIZE]
    const float* __restrict__ p_lse,   // [NUM_HEADS, NUM_TOKENS]
    const float* __restrict__ s_out,   // [NUM_TOKENS, NUM_HEADS, HEAD_SIZE]
    const float* __restrict__ s_lse,   // [NUM_HEADS, NUM_TOKENS]
    float* __restrict__ out,           // [NUM_TOKENS, NUM_HEADS, HEAD_SIZE]
    float* __restrict__ out_lse)       // [NUM_HEADS, NUM_TOKENS]
{
    const int pair = blockIdx.x * 8 + (threadIdx.x >> 5);  // token*32 + head
    const int lane = threadIdx.x & 31;
    const int head  = pair & (NUM_HEADS - 1);
    const int token = pair >> 5;  // log2(NUM_HEADS) = 5

    const int lse_idx = head * NUM_TOKENS + token;

    float pl = p_lse[lse_idx];
    float sl = s_lse[lse_idx];
    // +inf -> -inf sanitization (matches vLLM merge_attn_states)
    if (isinf(pl) && pl > 0.0f) pl = -INFINITY;
    if (isinf(sl) && sl > 0.0f) sl = -INFINITY;

    const float m  = fmaxf(pl, sl);
    const float pe = expf(pl - m);
    const float se = expf(sl - m);
    const float denom = pe + se;
    const float inv_denom = 1.0f / denom;
    const float p_scale = pe * inv_denom;
    const float s_scale = se * inv_denom;

    if (lane == 0) {
        out_lse[lse_idx] = logf(denom) + m;
    }

    const size_t base = (size_t)pair * HEAD_SIZE;
    const float4* pv = reinterpret_cast<const float4*>(p_out + base);
    const float4* sv = reinterpret_cast<const float4*>(s_out + base);
    float4*       ov = reinterpret_cast<float4*>(out + base);

    float4 a = pv[lane];
    float4 b = sv[lane];
    float4 r;
    r.x = a.x * p_scale + b.x * s_scale;
    r.y = a.y * p_scale + b.y * s_scale;
    r.z = a.z * p_scale + b.z * s_scale;
    r.w = a.w * p_scale + b.w * s_scale;
    ov[lane] = r;
}

extern "C" void kernel_launch(void* const* d_in, const int* in_sizes, int n_in,
                              void* d_out, int out_size, void* d_ws, size_t ws_size,
                              hipStream_t stream) {
    const float* p_out = (const float*)d_in[0];  // prefix_output
    const float* p_lse = (const float*)d_in[1];  // prefix_lse
    const float* s_out = (const float*)d_in[2];  // suffix_output
    const float* s_lse = (const float*)d_in[3];  // suffix_lse

    float* out     = (float*)d_out;
    float* out_lse = (float*)d_out + (size_t)NUM_TOKENS * NUM_HEADS * HEAD_SIZE;

    const int total_pairs = NUM_TOKENS * NUM_HEADS;        // 524288
    const int pairs_per_block = 256 / 32;                  // 8
    const int blocks = total_pairs / pairs_per_block;      // 65536

    merge_attn_states_kernel<<<blocks, 256, 0, stream>>>(
        p_out, p_lse, s_out, s_lse, out, out_lse);
}